// Round 14
// baseline (310.702 us; speedup 1.0000x reference)
//
#include <hip/hip_runtime.h>
#include <hip/hip_bf16.h>
#include <math.h>

// Problem constants
#define B_   8
#define C_   512
#define NH_  8
#define HD_  64
#define NSP  1024            // H*W
#define M_   (B_*NSP)        // 8192 rows
#define NQKV 1536
#define SCALE_ 0.125f        // 1/sqrt(64)
#define S2L_  0.18033688f    // SCALE_ * log2(e)

// R14 DIAGNOSTIC (deliberate, round does double duty): qkv repeated 4x so
// its dispatch exceeds the ~44us harness fills -> rocprof shows FETCH_SIZE
// (H1/H2 swizzle discrimination) + t/rep + MfmaUtil. Revert next round.
#define REPS_QKV 4

typedef __attribute__((ext_vector_type(8))) __bf16 bf16x8;
typedef __attribute__((ext_vector_type(4))) float  f32x4;
typedef __attribute__((ext_vector_type(16))) float f32x16;

__device__ __forceinline__ unsigned short f2bf(float f) {
  unsigned int u = __float_as_uint(f);
  u = u + 0x7fffu + ((u >> 16) & 1u);   // round-to-nearest-even
  return (unsigned short)(u >> 16);
}

// packed f32x2 -> bf16x2 (v_cvt_pk_bf16_f32 on gfx950); a -> low 16
__device__ __forceinline__ unsigned int pk2bf(float a, float b) {
  __hip_bfloat162 t = __float22bfloat162_rn(make_float2(a, b));
  unsigned int u; __builtin_memcpy(&u, &t, 4);
  return u;
}

// async global->LDS 16B (dest = wave-uniform base + lane*16)
__device__ __forceinline__ void async16(const unsigned short* g, unsigned short* l) {
  __builtin_amdgcn_global_load_lds(
      (const __attribute__((address_space(1))) void*)g,
      (__attribute__((address_space(3))) void*)l, 16, 0, 0);
}

// ------------------------------------------------------- fused LayerNorm
// R7 structure.
__global__ __launch_bounds__(256) void ln_fused_kernel(
    const float* __restrict__ x, const float* __restrict__ gamma,
    const float* __restrict__ beta, const float* __restrict__ wqkv,
    const float* __restrict__ wproj, unsigned short* __restrict__ xn,
    unsigned short* __restrict__ wqkvT, unsigned short* __restrict__ wprojT) {
  __shared__ __align__(16) char smem[76032];   // tile 67584 + shs 4224 + shs2 4224
  __shared__ float smu[32], srs[32];
  int tid = threadIdx.x;
  if (blockIdx.x >= 256) {
    // weight transpose via LDS bounce: in [k][n] fp32 -> out [n][k] bf16
    float (*tile)[65] = (float(*)[65])smem;
    int tx = tid & 63, ty = tid >> 6;
    const float* W; unsigned short* WT; int NW, t;
    if (blockIdx.x < 448) { W = wqkv;  WT = wqkvT;  NW = NQKV; t = blockIdx.x - 256; }
    else                  { W = wproj; WT = wprojT; NW = C_;   t = blockIdx.x - 448; }
    int ntiles = NW >> 6;
    int kt = t / ntiles, nt = t - kt * ntiles;
    for (int i = ty; i < 64; i += 4)                      // read coalesced in n
      tile[i][tx] = W[(size_t)(kt * 64 + i) * NW + nt * 64 + tx];
    __syncthreads();
    for (int i = ty; i < 64; i += 4)                      // write rows of WT
      WT[(size_t)(nt * 64 + i) * C_ + kt * 64 + tx] = f2bf(tile[tx][i]);
    return;
  }
  float (*tile)[33] = (float(*)[33])smem;                    // [512][33]
  float (*shs)[33]  = (float(*)[33])(smem + 67584);          // [32][33]
  float (*shs2)[33] = (float(*)[33])(smem + 67584 + 4224);   // [32][33]
  int b = blockIdx.x >> 5, n0 = (blockIdx.x & 31) * 32;
  int tx8 = tid & 7, cy = tid >> 3;     // n-quad, c-base
  float s[4] = {}, q[4] = {};
  const float* xp = x + ((size_t)b * C_) * NSP + n0 + tx8 * 4;
#pragma unroll
  for (int i = 0; i < 16; i++) {
    int c = cy + i * 32;
    float4 v = *(const float4*)(xp + (size_t)c * NSP);
    tile[c][tx8 * 4 + 0] = v.x; tile[c][tx8 * 4 + 1] = v.y;
    tile[c][tx8 * 4 + 2] = v.z; tile[c][tx8 * 4 + 3] = v.w;
    s[0] += v.x; q[0] += v.x * v.x;  s[1] += v.y; q[1] += v.y * v.y;
    s[2] += v.z; q[2] += v.z * v.z;  s[3] += v.w; q[3] += v.w * v.w;
  }
#pragma unroll
  for (int j = 0; j < 4; j++) { shs[cy][tx8 * 4 + j] = s[j]; shs2[cy][tx8 * 4 + j] = q[j]; }
  __syncthreads();
  if (tid < 32) {                       // reduce 32 partials per n
    float S = 0.f, S2 = 0.f;
#pragma unroll
    for (int r = 0; r < 32; r++) { S += shs[r][tid]; S2 += shs2[r][tid]; }
    float mu = S * (1.0f / C_);
    float var = S2 * (1.0f / C_) - mu * mu;
    smu[tid] = mu;
    srs[tid] = rsqrtf(var + 1e-5f);
  }
  __syncthreads();
  int c2 = tid * 2;
  float g0 = gamma[c2], g1 = gamma[c2 + 1], be0 = beta[c2], be1 = beta[c2 + 1];
  unsigned short* op = xn + ((size_t)(b * NSP + n0)) * C_ + c2;
#pragma unroll
  for (int n = 0; n < 32; n++) {
    float mu = smu[n], rs = srs[n];
    float v0 = (tile[c2][n]     - mu) * rs * g0 + be0;
    float v1 = (tile[c2 + 1][n] - mu) * rs * g1 + be1;
    *(unsigned int*)(op + (size_t)n * C_) = pk2bf(v0, v1);   // coalesced u32
  }
}

// ------------------------------------------------------------- QKV GEMM
// R14: COUNTED-VMCNT 3-BUFFER PIPELINE (T4, the R11 attn transform, now
// aimed at the actual latency-bound kernel). R12/R13 evidence: 2770 cyc
// per K-step vs ~400 compute; __syncthreads' vmcnt(0) drain at depth 1
// serializes each step on loaded HBM latency (~2.5k cyc); hbm 3.1 TB/s
// (half of achievable) = symptom. Now: 3 x 16 KB buffers (48 KB, still
// 3 blocks/CU), prefetch 2 steps ahead, per-step s_waitcnt vmcnt(4)
// (own stage's 4 loads done; next stage's 4 fly across the barrier).
// Safety == R11: counted own-stage wait + barrier -> tile visible; WAR
// distance 2 barriers; full unroll -> literal waits (kt<15 -> 4, =15 -> 0),
// issue guard kt<14. R13 XCD swizzle retained (FETCH discriminates H1/H2).
__global__ __launch_bounds__(256, 3) void gemm_qkv_kernel(
    const unsigned short* __restrict__ A,
    const unsigned short* __restrict__ Bt,
    const float* __restrict__ bias,
    unsigned short* __restrict__ out0, unsigned short* __restrict__ out1) {
  __shared__ __align__(16) char smem[49152];   // [3] x (As 8K + Bs 8K)
  int tid = threadIdx.x;
  int wave = tid >> 6, lane = tid & 63, quad = lane >> 4, l15 = lane & 15;
  int id = blockIdx.x;                 // 0..767
  int xcd = id & 7, j = id >> 3;
  int mt_ = xcd * 8 + (j & 7);         // m-tile 0..63
  int nt_ = j >> 3;                    // n-tile 0..11
  int n0 = nt_ * 128, m0 = mt_ * 128;
  int wm = (wave >> 1) * 64, wn = (wave & 1) * 64;
  int srow = lane >> 2, schunk = (lane & 3) * 8;
  auto stage = [&](int k0, int buf) {
    unsigned short* As = (unsigned short*)(smem + buf * 16384);
    unsigned short* Bs = (unsigned short*)(smem + buf * 16384 + 8192);
#pragma unroll
    for (int jj = 0; jj < 2; jj++) {
      int r0 = (wave + 4 * jj) * 16;
      async16(A + (size_t)(m0 + r0 + srow) * 512 + k0 + schunk, As + r0 * 32 + lane * 8);
      async16(Bt + (size_t)(n0 + r0 + srow) * 512 + k0 + schunk, Bs + r0 * 32 + lane * 8);
    }
  };
  float bw[4];
#pragma unroll
  for (int nt = 0; nt < 4; nt++) bw[nt] = bias[n0 + wn + nt * 16 + l15];
  for (int rep = 0; rep < REPS_QKV; rep++) {
    f32x4 acc[4][4] = {};
    stage(0, 0);                 // 4 outstanding per wave
    stage(32, 1);                // 8 outstanding
#pragma unroll
    for (int kt = 0; kt < 16; kt++) {
      int cur = kt % 3;
      // wait own stage(kt) loads (4 newer stay in flight), then join
      if (kt < 15) asm volatile("s_waitcnt vmcnt(4)" ::: "memory");
      else         asm volatile("s_waitcnt vmcnt(0)" ::: "memory");
      __builtin_amdgcn_s_barrier();
      if (kt < 14) stage((kt + 2) * 32, (kt + 2) % 3);   // 2 steps ahead
      unsigned short* As = (unsigned short*)(smem + cur * 16384);
      unsigned short* Bs = (unsigned short*)(smem + cur * 16384 + 8192);
      bf16x8 a[4], bb[4];
#pragma unroll
      for (int mt = 0; mt < 4; mt++)
        a[mt] = *(const bf16x8*)(As + (wm + mt * 16 + l15) * 32 + quad * 8);
#pragma unroll
      for (int nt = 0; nt < 4; nt++)
        bb[nt] = *(const bf16x8*)(Bs + (wn + nt * 16 + l15) * 32 + quad * 8);
#pragma unroll
      for (int mt = 0; mt < 4; mt++)
#pragma unroll
        for (int nt = 0; nt < 4; nt++)
          acc[mt][nt] = __builtin_amdgcn_mfma_f32_16x16x32_bf16(
              a[mt], bb[nt], acc[mt][nt], 0, 0, 0);
    }
    __syncthreads();                 // all waves done reading tiles; reuse smem
    if (n0 < 1024) {
      float sc = ((n0 + wn) < 512) ? S2L_ : 1.0f;   // pre-scale Q for exp2 softmax
      unsigned short* buf = (unsigned short*)(smem + wave * 8192);   // [32][68]
#pragma unroll
      for (int p = 0; p < 2; p++) {  // two 32-row passes (LDS budget 8KB/wave)
#pragma unroll
        for (int mh = 0; mh < 2; mh++) {
          int mt = p * 2 + mh;
#pragma unroll
          for (int nt = 0; nt < 4; nt++)
#pragma unroll
            for (int r = 0; r < 4; r++)
              buf[(mh * 16 + quad * 4 + r) * 68 + nt * 16 + l15] =
                  f2bf((acc[mt][nt][r] + bw[nt]) * sc);
        }
        // wave-private buffer: ds_write->ds_read ordered by lgkmcnt
#pragma unroll
        for (int i = 0; i < 4; i++) {
          int row = i * 8 + (lane >> 3);
          const unsigned short* bp_ = &buf[row * 68 + (lane & 7) * 8];
          uint2 lo = *(const uint2*)bp_;
          uint2 hi = *(const uint2*)(bp_ + 4);
          *(uint4*)(out0 + (size_t)(m0 + wm + p * 32 + row) * 1024 +
                    n0 + wn + (lane & 7) * 8) = make_uint4(lo.x, lo.y, hi.x, hi.y);
        }
      }
    } else {
      // V blocks: bf16 transposed into vt[(b*512 + (col-1024))*1024 + n]
      unsigned short* buf = (unsigned short*)(smem + wave * 8192);   // [64][17]
      int b = m0 >> 10, nbase = m0 & 1023;
      for (int nc = 0; nc < 4; nc++) {
#pragma unroll
        for (int mt = 0; mt < 4; mt++)
#pragma unroll
          for (int r = 0; r < 4; r++)
            buf[(mt * 16 + quad * 4 + r) * 17 + l15] = f2bf(acc[mt][nc][r] + bw[nc]);
        // wave-private: ds ordering via lgkmcnt; lanes cover 64 m -> 128B rows
#pragma unroll
        for (int cl = 0; cl < 16; cl++) {
          int crel = n0 - 1024 + wn + nc * 16 + cl;
          out1[((size_t)b * C_ + crel) * NSP + nbase + wm + lane] = buf[lane * 17 + cl];
        }
      }
    }
    __syncthreads();                 // rep-end: bounce reads done before restage
  }
}

// ------------------------------------------------------------- proj GEMM
// R4 structure (kept): 64x128 tiles, 32x64 per wave, vectorized bounce.
__global__ __launch_bounds__(256) void gemm_proj_kernel(
    const unsigned short* __restrict__ A,
    const unsigned short* __restrict__ Bt,
    const float* __restrict__ bias,
    float* __restrict__ O) {
  __shared__ __align__(16) char smem[24576];   // [2] x (As 4K + Bs 8K)
  int tid = threadIdx.x;
  int wave = tid >> 6, lane = tid & 63, quad = lane >> 4, l15 = lane & 15;
  int n0 = blockIdx.x * 128, m0 = blockIdx.y * 64;
  int wm = (wave >> 1) * 32, wn = (wave & 1) * 64;
  int srow = lane >> 2, schunk = (lane & 3) * 8;
  auto stage = [&](int k0, int buf) {
    unsigned short* As = (unsigned short*)(smem + buf * 12288);
    unsigned short* Bs = (unsigned short*)(smem + buf * 12288 + 4096);
    async16(A + (size_t)(m0 + wave * 16 + srow) * 512 + k0 + schunk,
            As + wave * 16 * 32 + lane * 8);
#pragma unroll
    for (int j = 0; j < 2; j++) {
      int r0 = (wave + 4 * j) * 16;
      async16(Bt + (size_t)(n0 + r0 + srow) * 512 + k0 + schunk, Bs + r0 * 32 + lane * 8);
    }
  };
  f32x4 acc[2][4] = {};
  stage(0, 0);
  for (int kt = 0; kt < 16; kt++) {
    int cur = kt & 1;
    __syncthreads();
    if (kt < 15) stage((kt + 1) * 32, cur ^ 1);
    unsigned short* As = (unsigned short*)(smem + cur * 12288);
    unsigned short* Bs = (unsigned short*)(smem + cur * 12288 + 4096);
    bf16x8 a[2], bb[4];
#pragma unroll
    for (int mt = 0; mt < 2; mt++)
      a[mt] = *(const bf16x8*)(As + (wm + mt * 16 + l15) * 32 + quad * 8);
#pragma unroll
    for (int nt = 0; nt < 4; nt++)
      bb[nt] = *(const bf16x8*)(Bs + (wn + nt * 16 + l15) * 32 + quad * 8);
#pragma unroll
    for (int mt = 0; mt < 2; mt++)
#pragma unroll
      for (int nt = 0; nt < 4; nt++)
        acc[mt][nt] = __builtin_amdgcn_mfma_f32_16x16x32_bf16(
            a[mt], bb[nt], acc[mt][nt], 0, 0, 0);
  }
  __syncthreads();                        // all waves done reading tiles
  float bw[4];
#pragma unroll
  for (int nt = 0; nt < 4; nt++) bw[nt] = bias[n0 + wn + nt * 16 + l15];
  float* buf = (float*)(smem + wave * 6144);   // [32][17] fp32 per wave
  int b = m0 >> 10, nbase = m0 & 1023;
  int ml = lane & 31, cg = lane >> 5;
  for (int nc = 0; nc < 4; nc++) {
#pragma unroll
    for (int mt = 0; mt < 2; mt++)
#pragma unroll
      for (int r = 0; r < 4; r++)
        buf[(mt * 16 + quad * 4 + r) * 17 + l15] = acc[mt][nc][r] + bw[nc];
    // wave-private: ds_write->ds_read ordering by lgkmcnt; 32-lane m rows
#pragma unroll
    for (int j = 0; j < 8; j++) {
      int cl = j * 2 + cg;
      int c = n0 + wn + nc * 16 + cl;
      O[((size_t)b * C_ + c) * NSP + nbase + wm + ml] = buf[ml * 17 + cl];
    }
  }
}

// ------------------------------------------------------- flash attention
// R11 verbatim (25.6us): counted-vmcnt 3-buffer pipeline, 32q/wave +
// kh split, ones-MFMA lsum, setprio, chunk-major V granules,
// in-register softmax.
__global__ __launch_bounds__(256, 3) void attn_kernel(
    const unsigned short* __restrict__ qk,
    const unsigned short* __restrict__ vt,
    unsigned short* __restrict__ o_ws) {
  __shared__ __align__(16) unsigned short Ks[3][2][32][64];     // [buf][kh][key][d]
  __shared__ __align__(16) unsigned short Vts[3][2][4][64][8];  // [buf][kh][kchunk][d][8key]
  int tid = threadIdx.x;
  int wave = tid >> 6, lane = tid & 63;
  int l31 = lane & 31, hi = lane >> 5;
  int qw = wave & 1, kh = wave >> 1;
  int b = blockIdx.x >> 3, h = blockIdx.x & 7;
  int qb = blockIdx.y * 64 + qw * 32;           // this wave's q-base (32 rows)
  int sc8 = lane & 7, sr8 = lane >> 3;          // K staging: chunk, row-in-8
  int swz = sc8 ^ sr8;                          // pre-swizzled source chunk
  uint4 ones4 = make_uint4(0x3F803F80u, 0x3F803F80u, 0x3F803F80u, 0x3F803F80u);
  bf16x8 aones; __builtin_memcpy(&aones, &ones4, 16);
  bf16x8 bq[4];
#pragma unroll
  for (int ks = 0; ks < 4; ks++)
    bq[ks] = *(const bf16x8*)(
        qk + (size_t)(b * NSP + qb + l31) * 1024 + h * 64 + ks * 16 + hi * 8);
  auto stage = [&](int it, int buf) {
    int k0 = kh * 512 + it * 32;
#pragma unroll
    for (int j = 0; j < 2; j++) {
      int row = qw * 16 + j * 8;
      async16(qk + (size_t)(b * NSP + k0 + row + sr8) * 1024 + 512 + h * 64 + swz * 8,
              &Ks[buf][kh][row][0]);
      int ch = qw * 2 + j;
      async16(vt + ((size_t)(b * C_ + h * 64 + lane)) * NSP + k0 + ch * 8,
              &Vts[buf][kh][ch][0][0]);
    }
  };
  f32x16 ot[2] = {};           // O^T accum [d-half]
  f32x16 lacc = {};            // lsum accum (all rows identical per q)
  stage(0, 0);                 // 4 outstanding
  stage(1, 1);                 // 8 outstanding
#pragma unroll
  for (int it = 0; it < 16; it++) {
    int cur = it % 3;
    if (it < 15) asm volatile("s_waitcnt vmcnt(4)" ::: "memory");
    else         asm volatile("s_waitcnt vmcnt(0)" ::: "memory");
    __builtin_amdgcn_s_barrier();
    if (it < 14) stage(it + 2, (it + 2) % 3);   // keep 2 tiles in flight
    f32x16 s = {};
    __builtin_amdgcn_s_setprio(1);
#pragma unroll
    for (int ks = 0; ks < 4; ks++) {
      bf16x8 ak = *(const bf16x8*)(
          &Ks[cur][kh][l31][((ks * 2 + hi) ^ (l31 & 7)) * 8]);
      s = __builtin_amdgcn_mfma_f32_32x32x16_bf16(ak, bq[ks], s, 0, 0, 0);
    }
    __builtin_amdgcn_s_setprio(0);
    float p0 = __builtin_amdgcn_exp2f(s[0]),  p1 = __builtin_amdgcn_exp2f(s[1]);
    float p2 = __builtin_amdgcn_exp2f(s[2]),  p3 = __builtin_amdgcn_exp2f(s[3]);
    float p4 = __builtin_amdgcn_exp2f(s[4]),  p5 = __builtin_amdgcn_exp2f(s[5]);
    float p6 = __builtin_amdgcn_exp2f(s[6]),  p7 = __builtin_amdgcn_exp2f(s[7]);
    float p8 = __builtin_amdgcn_exp2f(s[8]),  p9 = __builtin_amdgcn_exp2f(s[9]);
    float pa = __builtin_amdgcn_exp2f(s[10]), pb = __builtin_amdgcn_exp2f(s[11]);
    float pc = __builtin_amdgcn_exp2f(s[12]), pd = __builtin_amdgcn_exp2f(s[13]);
    float pe = __builtin_amdgcn_exp2f(s[14]), pf = __builtin_amdgcn_exp2f(s[15]);
    unsigned int d0 = pk2bf(p0, p1), d1 = pk2bf(p2, p3);
    unsigned int d2 = pk2bf(p4, p5), d3 = pk2bf(p6, p7);
    unsigned int d4 = pk2bf(p8, p9), d5 = pk2bf(pa, pb);
    unsigned int d6 = pk2bf(pc, pd), d7 = pk2bf(pe, pf);
    asm volatile("v_permlane32_swap_b32 %0, %1" : "+v"(d0), "+v"(d2));
    asm volatile("v_permlane32_swap_b32 %0, %1" : "+v"(d1), "+v"(d3));
    asm volatile("v_permlane32_swap_b32 %0, %1" : "+v"(d4), "+v"(d6));
    asm volatile("v_permlane32_swap_b32 %0, %1" : "+v"(d5), "+v"(d7));
    bf16x8 bp[2];
    uint4 f0 = make_uint4(d0, d1, d2, d3);   // keys 0..15 of tile
    uint4 f1 = make_uint4(d4, d5, d6, d7);   // keys 16..31
    __builtin_memcpy(&bp[0], &f0, 16);
    __builtin_memcpy(&bp[1], &f1, 16);
    __builtin_amdgcn_s_setprio(1);
#pragma unroll
    for (int kc = 0; kc < 2; kc++) {
      bf16x8 av0 = *(const bf16x8*)(&Vts[cur][kh][kc * 2 + hi][l31][0]);
      bf16x8 av1 = *(const bf16x8*)(&Vts[cur][kh][kc * 2 + hi][32 + l31][0]);
      ot[0] = __builtin_amdgcn_mfma_f32_32x32x16_bf16(av0, bp[kc], ot[0], 0, 0, 0);
      ot[1] = __builtin_amdgcn_mfma_f32_32x32x16_bf16(av1, bp[kc], ot[1], 0, 0, 0);
      lacc  = __builtin_amdgcn_mfma_f32_32x32x16_bf16(aones, bp[kc], lacc, 0, 0, 0);
    }
    __builtin_amdgcn_s_setprio(0);
  }
  __syncthreads();                       // full drain OK in epilogue
  float* Cb = (float*)&Ks[0][0][0][0];   // 2qw x 2dh x 16e x 64lane = 16 KB
  float* Lb = (float*)&Vts[0][0][0][0][0];
  if (kh == 1) {
#pragma unroll
    for (int dh = 0; dh < 2; dh++)
#pragma unroll
      for (int e = 0; e < 16; e++)
        Cb[((qw * 2 + dh) * 16 + e) * 64 + lane] = ot[dh][e];   // conflict-free
    Lb[qw * 64 + lane] = lacc[0];
  }
  __syncthreads();
  if (kh == 0) {
#pragma unroll
    for (int dh = 0; dh < 2; dh++)
#pragma unroll
      for (int e = 0; e < 16; e++)
        ot[dh][e] += Cb[((qw * 2 + dh) * 16 + e) * 64 + lane];
    float lv = lacc[0] + Lb[qw * 64 + lane];   // complete per-q sum, every lane
    float inv = 1.f / lv;
    unsigned short* orow = o_ws + (size_t)(b * NSP + qb + l31) * 512 + h * 64;
#pragma unroll
    for (int g = 0; g < 4; g++) {      // d = dh*32 + 8*g + 4*hi + {0..3}
      int d0 = 8 * g + 4 * hi;
      *(uint2*)(orow + d0) =
          make_uint2(pk2bf(ot[0][4 * g + 0] * inv, ot[0][4 * g + 1] * inv),
                     pk2bf(ot[0][4 * g + 2] * inv, ot[0][4 * g + 3] * inv));
      *(uint2*)(orow + 32 + d0) =
          make_uint2(pk2bf(ot[1][4 * g + 0] * inv, ot[1][4 * g + 1] * inv),
                     pk2bf(ot[1][4 * g + 2] * inv, ot[1][4 * g + 3] * inv));
    }
  }
}

// ------------------------------------------------------------------ launch
extern "C" void kernel_launch(void* const* d_in, const int* in_sizes, int n_in,
                              void* d_out, int out_size, void* d_ws, size_t ws_size,
                              hipStream_t stream) {
  const float* x     = (const float*)d_in[0];
  const float* gamma = (const float*)d_in[1];
  const float* beta  = (const float*)d_in[2];
  const float* wqkv  = (const float*)d_in[3];
  const float* bqkv  = (const float*)d_in[4];
  const float* wproj = (const float*)d_in[5];
  const float* bproj = (const float*)d_in[6];
  char* ws = (char*)d_ws;
  // workspace layout (~36 MB; o_bf aliases xn_bf — xn dead after QKV GEMM)
  unsigned short* wqkvT  = (unsigned short*)(ws + 262144);    // 1.5 MB
  unsigned short* wprojT = (unsigned short*)(ws + 1835008);   // 0.5 MB
  unsigned short* qk_bf  = (unsigned short*)(ws + 2359296);   //  16 MB [m][1024]
  unsigned short* vt_bf  = (unsigned short*)(ws + 19136512);  //   8 MB [b*512+c][n]
  unsigned short* xn_bf  = (unsigned short*)(ws + 27525120);  //   8 MB
  unsigned short* o_bf   = xn_bf;                             //   8 MB (alias)
  float* out = (float*)d_out;

  ln_fused_kernel<<<256 + 192 + 64, 256, 0, stream>>>(
      x, gamma, beta, wqkv, wproj, xn_bf, wqkvT, wprojT);
  gemm_qkv_kernel<<<768, 256, 0, stream>>>(
      xn_bf, wqkvT, bqkv, qk_bf, vt_bf);
  attn_kernel<<<dim3(B_ * NH_, NSP / 64), 256, 0, stream>>>(qk_bf, vt_bf, o_bf);
  gemm_proj_kernel<<<dim3(C_ / 128, M_ / 64), 256, 0, stream>>>(
      o_bf, wprojT, bproj, out);
}

// Round 17
// 145.130 us; speedup vs baseline: 2.1409x; 2.1409x over previous
//
#include <hip/hip_runtime.h>
#include <hip/hip_bf16.h>
#include <math.h>

// Problem constants
#define B_   8
#define C_   512
#define NH_  8
#define HD_  64
#define NSP  1024            // H*W
#define M_   (B_*NSP)        // 8192 rows
#define NQKV 1536
#define SCALE_ 0.125f        // 1/sqrt(64)
#define S2L_  0.18033688f    // SCALE_ * log2(e)

typedef __attribute__((ext_vector_type(8))) __bf16 bf16x8;
typedef __attribute__((ext_vector_type(4))) float  f32x4;
typedef __attribute__((ext_vector_type(16))) float f32x16;

__device__ __forceinline__ unsigned short f2bf(float f) {
  unsigned int u = __float_as_uint(f);
  u = u + 0x7fffu + ((u >> 16) & 1u);   // round-to-nearest-even
  return (unsigned short)(u >> 16);
}

// packed f32x2 -> bf16x2 (v_cvt_pk_bf16_f32 on gfx950); a -> low 16
__device__ __forceinline__ unsigned int pk2bf(float a, float b) {
  __hip_bfloat162 t = __float22bfloat162_rn(make_float2(a, b));
  unsigned int u; __builtin_memcpy(&u, &t, 4);
  return u;
}

// async global->LDS 16B (dest = wave-uniform base + lane*16)
__device__ __forceinline__ void async16(const unsigned short* g, unsigned short* l) {
  __builtin_amdgcn_global_load_lds(
      (const __attribute__((address_space(1))) void*)g,
      (__attribute__((address_space(3))) void*)l, 16, 0, 0);
}

// ------------------------------------------------------- fused LayerNorm
// R7 structure (passing version).
__global__ __launch_bounds__(256) void ln_fused_kernel(
    const float* __restrict__ x, const float* __restrict__ gamma,
    const float* __restrict__ beta, const float* __restrict__ wqkv,
    const float* __restrict__ wproj, unsigned short* __restrict__ xn,
    unsigned short* __restrict__ wqkvT, unsigned short* __restrict__ wprojT) {
  __shared__ __align__(16) char smem[76032];   // tile 67584 + shs 4224 + shs2 4224
  __shared__ float smu[32], srs[32];
  int tid = threadIdx.x;
  if (blockIdx.x >= 256) {
    // weight transpose via LDS bounce: in [k][n] fp32 -> out [n][k] bf16
    float (*tile)[65] = (float(*)[65])smem;
    int tx = tid & 63, ty = tid >> 6;
    const float* W; unsigned short* WT; int NW, t;
    if (blockIdx.x < 448) { W = wqkv;  WT = wqkvT;  NW = NQKV; t = blockIdx.x - 256; }
    else                  { W = wproj; WT = wprojT; NW = C_;   t = blockIdx.x - 448; }
    int ntiles = NW >> 6;
    int kt = t / ntiles, nt = t - kt * ntiles;
    for (int i = ty; i < 64; i += 4)                      // read coalesced in n
      tile[i][tx] = W[(size_t)(kt * 64 + i) * NW + nt * 64 + tx];
    __syncthreads();
    for (int i = ty; i < 64; i += 4)                      // write rows of WT
      WT[(size_t)(nt * 64 + i) * C_ + kt * 64 + tx] = f2bf(tile[tx][i]);
    return;
  }
  float (*tile)[33] = (float(*)[33])smem;                    // [512][33]
  float (*shs)[33]  = (float(*)[33])(smem + 67584);          // [32][33]
  float (*shs2)[33] = (float(*)[33])(smem + 67584 + 4224);   // [32][33]
  int b = blockIdx.x >> 5, n0 = (blockIdx.x & 31) * 32;
  int tx8 = tid & 7, cy = tid >> 3;     // n-quad, c-base
  float s[4] = {}, q[4] = {};
  const float* xp = x + ((size_t)b * C_) * NSP + n0 + tx8 * 4;
#pragma unroll
  for (int i = 0; i < 16; i++) {
    int c = cy + i * 32;
    float4 v = *(const float4*)(xp + (size_t)c * NSP);
    tile[c][tx8 * 4 + 0] = v.x; tile[c][tx8 * 4 + 1] = v.y;
    tile[c][tx8 * 4 + 2] = v.z; tile[c][tx8 * 4 + 3] = v.w;
    s[0] += v.x; q[0] += v.x * v.x;  s[1] += v.y; q[1] += v.y * v.y;
    s[2] += v.z; q[2] += v.z * v.z;  s[3] += v.w; q[3] += v.w * v.w;
  }
#pragma unroll
  for (int j = 0; j < 4; j++) { shs[cy][tx8 * 4 + j] = s[j]; shs2[cy][tx8 * 4 + j] = q[j]; }
  __syncthreads();
  if (tid < 32) {                       // reduce 32 partials per n
    float S = 0.f, S2 = 0.f;
#pragma unroll
    for (int r = 0; r < 32; r++) { S += shs[r][tid]; S2 += shs2[r][tid]; }
    float mu = S * (1.0f / C_);
    float var = S2 * (1.0f / C_) - mu * mu;
    smu[tid] = mu;
    srs[tid] = rsqrtf(var + 1e-5f);
  }
  __syncthreads();
  int c2 = tid * 2;
  float g0 = gamma[c2], g1 = gamma[c2 + 1], be0 = beta[c2], be1 = beta[c2 + 1];
  unsigned short* op = xn + ((size_t)(b * NSP + n0)) * C_ + c2;
#pragma unroll
  for (int n = 0; n < 32; n++) {
    float mu = smu[n], rs = srs[n];
    float v0 = (tile[c2][n]     - mu) * rs * g0 + be0;
    float v1 = (tile[c2 + 1][n] - mu) * rs * g1 + be1;
    *(unsigned int*)(op + (size_t)n * C_) = pk2bf(v0, v1);   // coalesced u32
  }
}

// ------------------------------------------------------------- QKV GEMM
// R14 body with REPS=1 (all components harness-verified):
// static id&7 XCD swizzle (R13) + counted-vmcnt 3-buffer pipeline (R14).
__global__ __launch_bounds__(256, 3) void gemm_qkv_kernel(
    const unsigned short* __restrict__ A,
    const unsigned short* __restrict__ Bt,
    const float* __restrict__ bias,
    unsigned short* __restrict__ out0, unsigned short* __restrict__ out1) {
  __shared__ __align__(16) char smem[49152];   // [3] x (As 8K + Bs 8K)
  int tid = threadIdx.x;
  int wave = tid >> 6, lane = tid & 63, quad = lane >> 4, l15 = lane & 15;
  int id = blockIdx.x;                 // 0..767
  int xcd = id & 7, j = id >> 3;
  int mt_ = xcd * 8 + (j & 7);         // m-tile 0..63
  int nt_ = j >> 3;                    // n-tile 0..11
  int n0 = nt_ * 128, m0 = mt_ * 128;
  int wm = (wave >> 1) * 64, wn = (wave & 1) * 64;
  int srow = lane >> 2, schunk = (lane & 3) * 8;
  auto stage = [&](int k0, int buf) {
    unsigned short* As = (unsigned short*)(smem + buf * 16384);
    unsigned short* Bs = (unsigned short*)(smem + buf * 16384 + 8192);
#pragma unroll
    for (int jj = 0; jj < 2; jj++) {
      int r0 = (wave + 4 * jj) * 16;
      async16(A + (size_t)(m0 + r0 + srow) * 512 + k0 + schunk, As + r0 * 32 + lane * 8);
      async16(Bt + (size_t)(n0 + r0 + srow) * 512 + k0 + schunk, Bs + r0 * 32 + lane * 8);
    }
  };
  float bw[4];
#pragma unroll
  for (int nt = 0; nt < 4; nt++) bw[nt] = bias[n0 + wn + nt * 16 + l15];
  f32x4 acc[4][4] = {};
  stage(0, 0);                 // 4 outstanding per wave
  stage(32, 1);                // 8 outstanding
#pragma unroll
  for (int kt = 0; kt < 16; kt++) {
    int cur = kt % 3;
    // wait own stage(kt) loads (4 newer stay in flight), then join
    if (kt < 15) asm volatile("s_waitcnt vmcnt(4)" ::: "memory");
    else         asm volatile("s_waitcnt vmcnt(0)" ::: "memory");
    __builtin_amdgcn_s_barrier();
    if (kt < 14) stage((kt + 2) * 32, (kt + 2) % 3);   // 2 steps ahead
    unsigned short* As = (unsigned short*)(smem + cur * 16384);
    unsigned short* Bs = (unsigned short*)(smem + cur * 16384 + 8192);
    bf16x8 a[4], bb[4];
#pragma unroll
    for (int mt = 0; mt < 4; mt++)
      a[mt] = *(const bf16x8*)(As + (wm + mt * 16 + l15) * 32 + quad * 8);
#pragma unroll
    for (int nt = 0; nt < 4; nt++)
      bb[nt] = *(const bf16x8*)(Bs + (wn + nt * 16 + l15) * 32 + quad * 8);
#pragma unroll
    for (int mt = 0; mt < 4; mt++)
#pragma unroll
      for (int nt = 0; nt < 4; nt++)
        acc[mt][nt] = __builtin_amdgcn_mfma_f32_16x16x32_bf16(
            a[mt], bb[nt], acc[mt][nt], 0, 0, 0);
  }
  __syncthreads();                 // all waves done reading tiles; reuse smem
  if (n0 < 1024) {
    float sc = ((n0 + wn) < 512) ? S2L_ : 1.0f;   // pre-scale Q for exp2 softmax
    unsigned short* buf = (unsigned short*)(smem + wave * 8192);   // [32][68]
#pragma unroll
    for (int p = 0; p < 2; p++) {  // two 32-row passes (LDS budget 8KB/wave)
#pragma unroll
      for (int mh = 0; mh < 2; mh++) {
        int mt = p * 2 + mh;
#pragma unroll
        for (int nt = 0; nt < 4; nt++)
#pragma unroll
          for (int r = 0; r < 4; r++)
            buf[(mh * 16 + quad * 4 + r) * 68 + nt * 16 + l15] =
                f2bf((acc[mt][nt][r] + bw[nt]) * sc);
      }
      // wave-private buffer: ds_write->ds_read ordered by lgkmcnt
#pragma unroll
      for (int i = 0; i < 4; i++) {
        int row = i * 8 + (lane >> 3);
        const unsigned short* bp_ = &buf[row * 68 + (lane & 7) * 8];
        uint2 lo = *(const uint2*)bp_;
        uint2 hi = *(const uint2*)(bp_ + 4);
        *(uint4*)(out0 + (size_t)(m0 + wm + p * 32 + row) * 1024 +
                  n0 + wn + (lane & 7) * 8) = make_uint4(lo.x, lo.y, hi.x, hi.y);
      }
    }
  } else {
    // V blocks: bf16 transposed into vt[(b*512 + (col-1024))*1024 + n]
    unsigned short* buf = (unsigned short*)(smem + wave * 8192);   // [64][17]
    int b = m0 >> 10, nbase = m0 & 1023;
    for (int nc = 0; nc < 4; nc++) {
#pragma unroll
      for (int mt = 0; mt < 4; mt++)
#pragma unroll
        for (int r = 0; r < 4; r++)
          buf[(mt * 16 + quad * 4 + r) * 17 + l15] = f2bf(acc[mt][nc][r] + bw[nc]);
      // wave-private: ds ordering via lgkmcnt; lanes cover 64 m -> 128B rows
#pragma unroll
      for (int cl = 0; cl < 16; cl++) {
        int crel = n0 - 1024 + wn + nc * 16 + cl;
        out1[((size_t)b * C_ + crel) * NSP + nbase + wm + lane] = buf[lane * 17 + cl];
      }
    }
  }
}

// ------------------------------------------------------------- proj GEMM
// Counted-vmcnt 3-buffer pipeline (same proven transform as qkv/attn;
// per-wave 3 loads/stage -> vmcnt(3); 36 KB LDS; WAR distance 2 barriers).
__global__ __launch_bounds__(256) void gemm_proj_kernel(
    const unsigned short* __restrict__ A,
    const unsigned short* __restrict__ Bt,
    const float* __restrict__ bias,
    float* __restrict__ O) {
  __shared__ __align__(16) char smem[36864];   // [3] x (As 4K + Bs 8K)
  int tid = threadIdx.x;
  int wave = tid >> 6, lane = tid & 63, quad = lane >> 4, l15 = lane & 15;
  int n0 = blockIdx.x * 128, m0 = blockIdx.y * 64;
  int wm = (wave >> 1) * 32, wn = (wave & 1) * 64;
  int srow = lane >> 2, schunk = (lane & 3) * 8;
  auto stage = [&](int k0, int buf) {
    unsigned short* As = (unsigned short*)(smem + buf * 12288);
    unsigned short* Bs = (unsigned short*)(smem + buf * 12288 + 4096);
    async16(A + (size_t)(m0 + wave * 16 + srow) * 512 + k0 + schunk,
            As + wave * 16 * 32 + lane * 8);
#pragma unroll
    for (int j = 0; j < 2; j++) {
      int r0 = (wave + 4 * j) * 16;
      async16(Bt + (size_t)(n0 + r0 + srow) * 512 + k0 + schunk, Bs + r0 * 32 + lane * 8);
    }
  };
  float bw[4];
#pragma unroll
  for (int nt = 0; nt < 4; nt++) bw[nt] = bias[n0 + wn + nt * 16 + l15];
  f32x4 acc[2][4] = {};
  stage(0, 0);                 // 3 outstanding per wave
  stage(32, 1);                // 6 outstanding
#pragma unroll
  for (int kt = 0; kt < 16; kt++) {
    int cur = kt % 3;
    if (kt < 15) asm volatile("s_waitcnt vmcnt(3)" ::: "memory");
    else         asm volatile("s_waitcnt vmcnt(0)" ::: "memory");
    __builtin_amdgcn_s_barrier();
    if (kt < 14) stage((kt + 2) * 32, (kt + 2) % 3);   // 2 steps ahead
    unsigned short* As = (unsigned short*)(smem + cur * 12288);
    unsigned short* Bs = (unsigned short*)(smem + cur * 12288 + 4096);
    bf16x8 a[2], bb[4];
#pragma unroll
    for (int mt = 0; mt < 2; mt++)
      a[mt] = *(const bf16x8*)(As + (wm + mt * 16 + l15) * 32 + quad * 8);
#pragma unroll
    for (int nt = 0; nt < 4; nt++)
      bb[nt] = *(const bf16x8*)(Bs + (wn + nt * 16 + l15) * 32 + quad * 8);
#pragma unroll
    for (int mt = 0; mt < 2; mt++)
#pragma unroll
      for (int nt = 0; nt < 4; nt++)
        acc[mt][nt] = __builtin_amdgcn_mfma_f32_16x16x32_bf16(
            a[mt], bb[nt], acc[mt][nt], 0, 0, 0);
  }
  __syncthreads();                        // all waves done reading tiles
  float* buf = (float*)(smem + wave * 6144);   // [32][17] fp32 per wave
  int b = m0 >> 10, nbase = m0 & 1023;
  int ml = lane & 31, cg = lane >> 5;
  for (int nc = 0; nc < 4; nc++) {
#pragma unroll
    for (int mt = 0; mt < 2; mt++)
#pragma unroll
      for (int r = 0; r < 4; r++)
        buf[(mt * 16 + quad * 4 + r) * 17 + l15] = acc[mt][nc][r] + bw[nc];
    // wave-private: ds_write->ds_read ordering by lgkmcnt; 32-lane m rows
#pragma unroll
    for (int j = 0; j < 8; j++) {
      int cl = j * 2 + cg;
      int c = n0 + wn + nc * 16 + cl;
      O[((size_t)b * C_ + c) * NSP + nbase + wm + ml] = buf[ml * 17 + cl];
    }
  }
}

// ------------------------------------------------------- flash attention
// R11 verbatim (25.6us, passing): counted-vmcnt 3-buffer pipeline,
// 32q/wave + kh split, ones-MFMA lsum, setprio, chunk-major V granules,
// in-register softmax.
__global__ __launch_bounds__(256, 3) void attn_kernel(
    const unsigned short* __restrict__ qk,
    const unsigned short* __restrict__ vt,
    unsigned short* __restrict__ o_ws) {
  __shared__ __align__(16) unsigned short Ks[3][2][32][64];     // [buf][kh][key][d]
  __shared__ __align__(16) unsigned short Vts[3][2][4][64][8];  // [buf][kh][kchunk][d][8key]
  int tid = threadIdx.x;
  int wave = tid >> 6, lane = tid & 63;
  int l31 = lane & 31, hi = lane >> 5;
  int qw = wave & 1, kh = wave >> 1;
  int b = blockIdx.x >> 3, h = blockIdx.x & 7;
  int qb = blockIdx.y * 64 + qw * 32;           // this wave's q-base (32 rows)
  int sc8 = lane & 7, sr8 = lane >> 3;          // K staging: chunk, row-in-8
  int swz = sc8 ^ sr8;                          // pre-swizzled source chunk
  uint4 ones4 = make_uint4(0x3F803F80u, 0x3F803F80u, 0x3F803F80u, 0x3F803F80u);
  bf16x8 aones; __builtin_memcpy(&aones, &ones4, 16);
  bf16x8 bq[4];
#pragma unroll
  for (int ks = 0; ks < 4; ks++)
    bq[ks] = *(const bf16x8*)(
        qk + (size_t)(b * NSP + qb + l31) * 1024 + h * 64 + ks * 16 + hi * 8);
  auto stage = [&](int it, int buf) {
    int k0 = kh * 512 + it * 32;
#pragma unroll
    for (int j = 0; j < 2; j++) {
      int row = qw * 16 + j * 8;
      async16(qk + (size_t)(b * NSP + k0 + row + sr8) * 1024 + 512 + h * 64 + swz * 8,
              &Ks[buf][kh][row][0]);
      int ch = qw * 2 + j;
      async16(vt + ((size_t)(b * C_ + h * 64 + lane)) * NSP + k0 + ch * 8,
              &Vts[buf][kh][ch][0][0]);
    }
  };
  f32x16 ot[2] = {};           // O^T accum [d-half]
  f32x16 lacc = {};            // lsum accum (all rows identical per q)
  stage(0, 0);                 // 4 outstanding
  stage(1, 1);                 // 8 outstanding
#pragma unroll
  for (int it = 0; it < 16; it++) {
    int cur = it % 3;
    if (it < 15) asm volatile("s_waitcnt vmcnt(4)" ::: "memory");
    else         asm volatile("s_waitcnt vmcnt(0)" ::: "memory");
    __builtin_amdgcn_s_barrier();
    if (it < 14) stage(it + 2, (it + 2) % 3);   // keep 2 tiles in flight
    f32x16 s = {};
    __builtin_amdgcn_s_setprio(1);
#pragma unroll
    for (int ks = 0; ks < 4; ks++) {
      bf16x8 ak = *(const bf16x8*)(
          &Ks[cur][kh][l31][((ks * 2 + hi) ^ (l31 & 7)) * 8]);
      s = __builtin_amdgcn_mfma_f32_32x32x16_bf16(ak, bq[ks], s, 0, 0, 0);
    }
    __builtin_amdgcn_s_setprio(0);
    float p0 = __builtin_amdgcn_exp2f(s[0]),  p1 = __builtin_amdgcn_exp2f(s[1]);
    float p2 = __builtin_amdgcn_exp2f(s[2]),  p3 = __builtin_amdgcn_exp2f(s[3]);
    float p4 = __builtin_amdgcn_exp2f(s[4]),  p5 = __builtin_amdgcn_exp2f(s[5]);
    float p6 = __builtin_amdgcn_exp2f(s[6]),  p7 = __builtin_amdgcn_exp2f(s[7]);
    float p8 = __builtin_amdgcn_exp2f(s[8]),  p9 = __builtin_amdgcn_exp2f(s[9]);
    float pa = __builtin_amdgcn_exp2f(s[10]), pb = __builtin_amdgcn_exp2f(s[11]);
    float pc = __builtin_amdgcn_exp2f(s[12]), pd = __builtin_amdgcn_exp2f(s[13]);
    float pe = __builtin_amdgcn_exp2f(s[14]), pf = __builtin_amdgcn_exp2f(s[15]);
    unsigned int d0 = pk2bf(p0, p1), d1 = pk2bf(p2, p3);
    unsigned int d2 = pk2bf(p4, p5), d3 = pk2bf(p6, p7);
    unsigned int d4 = pk2bf(p8, p9), d5 = pk2bf(pa, pb);
    unsigned int d6 = pk2bf(pc, pd), d7 = pk2bf(pe, pf);
    asm volatile("v_permlane32_swap_b32 %0, %1" : "+v"(d0), "+v"(d2));
    asm volatile("v_permlane32_swap_b32 %0, %1" : "+v"(d1), "+v"(d3));
    asm volatile("v_permlane32_swap_b32 %0, %1" : "+v"(d4), "+v"(d6));
    asm volatile("v_permlane32_swap_b32 %0, %1" : "+v"(d5), "+v"(d7));
    bf16x8 bp[2];
    uint4 f0 = make_uint4(d0, d1, d2, d3);   // keys 0..15 of tile
    uint4 f1 = make_uint4(d4, d5, d6, d7);   // keys 16..31
    __builtin_memcpy(&bp[0], &f0, 16);
    __builtin_memcpy(&bp[1], &f1, 16);
    __builtin_amdgcn_s_setprio(1);
#pragma unroll
    for (int kc = 0; kc < 2; kc++) {
      bf16x8 av0 = *(const bf16x8*)(&Vts[cur][kh][kc * 2 + hi][l31][0]);
      bf16x8 av1 = *(const bf16x8*)(&Vts[cur][kh][kc * 2 + hi][32 + l31][0]);
      ot[0] = __builtin_amdgcn_mfma_f32_32x32x16_bf16(av0, bp[kc], ot[0], 0, 0, 0);
      ot[1] = __builtin_amdgcn_mfma_f32_32x32x16_bf16(av1, bp[kc], ot[1], 0, 0, 0);
      lacc  = __builtin_amdgcn_mfma_f32_32x32x16_bf16(aones, bp[kc], lacc, 0, 0, 0);
    }
    __builtin_amdgcn_s_setprio(0);
  }
  __syncthreads();                       // full drain OK in epilogue
  float* Cb = (float*)&Ks[0][0][0][0];   // 2qw x 2dh x 16e x 64lane = 16 KB
  float* Lb = (float*)&Vts[0][0][0][0][0];
  if (kh == 1) {
#pragma unroll
    for (int dh = 0; dh < 2; dh++)
#pragma unroll
      for (int e = 0; e < 16; e++)
        Cb[((qw * 2 + dh) * 16 + e) * 64 + lane] = ot[dh][e];   // conflict-free
    Lb[qw * 64 + lane] = lacc[0];
  }
  __syncthreads();
  if (kh == 0) {
#pragma unroll
    for (int dh = 0; dh < 2; dh++)
#pragma unroll
      for (int e = 0; e < 16; e++)
        ot[dh][e] += Cb[((qw * 2 + dh) * 16 + e) * 64 + lane];
    float lv = lacc[0] + Lb[qw * 64 + lane];   // complete per-q sum, every lane
    float inv = 1.f / lv;
    unsigned short* orow = o_ws + (size_t)(b * NSP + qb + l31) * 512 + h * 64;
#pragma unroll
    for (int g = 0; g < 4; g++) {      // d = dh*32 + 8*g + 4*hi + {0..3}
      int d0 = 8 * g + 4 * hi;
      *(uint2*)(orow + d0) =
          make_uint2(pk2bf(ot[0][4 * g + 0] * inv, ot[0][4 * g + 1] * inv),
                     pk2bf(ot[0][4 * g + 2] * inv, ot[0][4 * g + 3] * inv));
      *(uint2*)(orow + 32 + d0) =
          make_uint2(pk2bf(ot[1][4 * g + 0] * inv, ot[1][4 * g + 1] * inv),
                     pk2bf(ot[1][4 * g + 2] * inv, ot[1][4 * g + 3] * inv));
    }
  }
}

// ------------------------------------------------------------------ launch
extern "C" void kernel_launch(void* const* d_in, const int* in_sizes, int n_in,
                              void* d_out, int out_size, void* d_ws, size_t ws_size,
                              hipStream_t stream) {
  const float* x     = (const float*)d_in[0];
  const float* gamma = (const float*)d_in[1];
  const float* beta  = (const float*)d_in[2];
  const float* wqkv  = (const float*)d_in[3];
  const float* bqkv  = (const float*)d_in[4];
  const float* wproj = (const float*)d_in[5];
  const float* bproj = (const float*)d_in[6];
  char* ws = (char*)d_ws;
  // workspace layout (~36 MB; o_bf aliases xn_bf — xn dead after QKV GEMM)
  unsigned short* wqkvT  = (unsigned short*)(ws + 262144);    // 1.5 MB
  unsigned short* wprojT = (unsigned short*)(ws + 1835008);   // 0.5 MB
  unsigned short* qk_bf  = (unsigned short*)(ws + 2359296);   //  16 MB [m][1024]
  unsigned short* vt_bf  = (unsigned short*)(ws + 19136512);  //   8 MB [b*512+c][n]
  unsigned short* xn_bf  = (unsigned short*)(ws + 27525120);  //   8 MB
  unsigned short* o_bf   = xn_bf;                             //   8 MB (alias)
  float* out = (float*)d_out;

  ln_fused_kernel<<<256 + 192 + 64, 256, 0, stream>>>(
      x, gamma, beta, wqkv, wproj, xn_bf, wqkvT, wprojT);
  gemm_qkv_kernel<<<768, 256, 0, stream>>>(
      xn_bf, wqkvT, bqkv, qk_bf, vt_bf);
  attn_kernel<<<dim3(B_ * NH_, NSP / 64), 256, 0, stream>>>(qk_bf, vt_bf, o_bf);
  gemm_proj_kernel<<<dim3(C_ / 128, M_ / 64), 256, 0, stream>>>(
      o_bf, wprojT, bproj, out);
}